// Round 6
// baseline (410.397 us; speedup 1.0000x reference)
//
#include <hip/hip_runtime.h>

typedef unsigned short u16;
typedef __bf16 bf16x8 __attribute__((ext_vector_type(8)));
typedef float f32x4 __attribute__((ext_vector_type(4)));
typedef u16 u16x8 __attribute__((ext_vector_type(8)));
typedef u16 u16x4 __attribute__((ext_vector_type(4)));

static constexpr int S_LEN  = 2048;
static constexpr int DMODEL = 2048;
static constexpr int NKV    = 4;
static constexpr int HD     = 128;

__device__ __forceinline__ u16 f2bf(float f) {
  unsigned u = __builtin_bit_cast(unsigned, f);
  u += 0x7fffu + ((u >> 16) & 1u);
  return (u16)(u >> 16);
}
__device__ __forceinline__ float bf2f(u16 h) {
  unsigned u = ((unsigned)h) << 16;
  return __builtin_bit_cast(float, u);
}
__device__ __forceinline__ bf16x8 as_bf(u16x8 v) { return __builtin_bit_cast(bf16x8, v); }

__device__ __forceinline__ u16x8 cvt8(const float* p) {
  f32x4 lo = *(const f32x4*)p;
  f32x4 hi = *(const f32x4*)(p + 4);
  u16x8 r;
#pragma unroll
  for (int j = 0; j < 4; ++j) { r[j] = f2bf(lo[j]); r[j + 4] = f2bf(hi[j]); }
  return r;
}

// async global->LDS DMA, 16B/lane; LDS dest = wave-uniform base + lane*16.
__device__ __forceinline__ void gld16(const u16* g, u16* l) {
  auto gp = (const __attribute__((address_space(1))) unsigned*)(unsigned long long)g;
  auto lp = (__attribute__((address_space(3))) unsigned*)(unsigned)(unsigned long long)l;
  __builtin_amdgcn_global_load_lds(gp, lp, 16, 0, 0);
}

// ---------------------------------------------------------------------------
// fp32 -> bf16 conversion kernels (unchanged)
// ---------------------------------------------------------------------------
__global__ __launch_bounds__(256) void cvt1(const float* __restrict__ in,
                                            u16* __restrict__ out, int n8) {
  const int i = blockIdx.x * 256 + threadIdx.x;
  if (i < n8) *(u16x8*)(out + (long)i * 8) = cvt8(in + (long)i * 8);
}
__global__ __launch_bounds__(256) void cvt3(const float* __restrict__ a,
                                            const float* __restrict__ b,
                                            const float* __restrict__ c,
                                            u16* __restrict__ out) {
  const int i = blockIdx.x * 256 + threadIdx.x;     // 786432 total
  const float* src; long j;
  if (i < 524288)      { src = a; j = i; }
  else if (i < 655360) { src = b; j = i - 524288; }
  else                 { src = c; j = i - 655360; }
  *(u16x8*)(out + (long)i * 8) = cvt8(src + j * 8);
}

// ---------------------------------------------------------------------------
// Fused QKV projection (unchanged from round 5 — verified)
// ---------------------------------------------------------------------------
__global__ __launch_bounds__(256) void gemm_qkv(
    const u16* __restrict__ A, const u16* __restrict__ Bw,
    u16* __restrict__ Cq, u16* __restrict__ Ck, u16* __restrict__ Cv)
{
  constexpr int K = 2048;
  __shared__ u16 As[128 * 32];
  __shared__ u16 Bs[128 * 32];
  const int bx = blockIdx.x;
  const int bm = bx / 24, bn = bx % 24;
  const int tid = threadIdx.x, wave = tid >> 6, lane = tid & 63;
  const int wm = (wave & 1) << 6, wn = (wave >> 1) << 6;
  const long m0 = (long)bm << 7, n0 = (long)bn << 7;

  f32x4 acc[4][4] = {};

  const int srow = (wave << 5) + (lane >> 2);
  const int sch  = (lane & 3) << 3;
  const u16* ga = A  + (m0 + srow) * K + sch;
  const u16* gb = Bw + (n0 + srow) * K + sch;
  u16* la = As + (wave << 10);
  u16* lb = Bs + (wave << 10);
  const long rstep = (long)16 * K;

  const int fr = lane & 15, fc = (lane >> 4) << 3;

  for (int k0 = 0; k0 < K; k0 += 32) {
    __syncthreads();
    gld16(ga + k0,         la);
    gld16(ga + k0 + rstep, la + 512);
    gld16(gb + k0,         lb);
    gld16(gb + k0 + rstep, lb + 512);
    __syncthreads();
    bf16x8 af[4], bf[4];
#pragma unroll
    for (int i = 0; i < 4; ++i)
      af[i] = as_bf(*(const u16x8*)&As[(wm + (i << 4) + fr) * 32 + fc]);
#pragma unroll
    for (int i = 0; i < 4; ++i)
      bf[i] = as_bf(*(const u16x8*)&Bs[(wn + (i << 4) + fr) * 32 + fc]);
#pragma unroll
    for (int mi = 0; mi < 4; ++mi)
#pragma unroll
      for (int ni = 0; ni < 4; ++ni)
        acc[mi][ni] = __builtin_amdgcn_mfma_f32_16x16x32_bf16(af[mi], bf[ni], acc[mi][ni], 0, 0, 0);
  }

  u16* Cb; int N2; long c0;
  if (bn < 16)      { Cb = Cq; N2 = 2048; c0 = n0; }
  else if (bn < 20) { Cb = Ck; N2 = 512;  c0 = n0 - 2048; }
  else              { Cb = Cv; N2 = 512;  c0 = n0 - 2560; }

  const int er = (lane >> 4) << 2, ec = lane & 15;
#pragma unroll
  for (int mi = 0; mi < 4; ++mi)
#pragma unroll
    for (int ni = 0; ni < 4; ++ni) {
      u16* cp = Cb + (m0 + wm + (mi << 4) + er) * N2 + (c0 + wn + (ni << 4) + ec);
#pragma unroll
      for (int r = 0; r < 4; ++r)
        cp[(long)r * N2] = f2bf(acc[mi][ni][r]);
    }
}

// ---------------------------------------------------------------------------
// Output projection (unchanged from round 5 — verified)
// ---------------------------------------------------------------------------
__global__ __launch_bounds__(256) void gemm_o(
    const u16* __restrict__ A, const u16* __restrict__ Bw, float* __restrict__ C)
{
  constexpr int K = 2048, N = 2048;
  __shared__ u16 As[128 * 32];
  __shared__ u16 Bs[128 * 32];
  const int bx = blockIdx.x;
  const int bm = bx >> 4, bn = bx & 15;
  const int tid = threadIdx.x, wave = tid >> 6, lane = tid & 63;
  const int wm = (wave & 1) << 6, wn = (wave >> 1) << 6;
  const long m0 = (long)bm << 7, n0 = (long)bn << 7;

  f32x4 acc[4][4] = {};

  const int srow = (wave << 5) + (lane >> 2);
  const int sch  = (lane & 3) << 3;
  const u16* ga = A  + (m0 + srow) * K + sch;
  const u16* gb = Bw + (n0 + srow) * K + sch;
  u16* la = As + (wave << 10);
  u16* lb = Bs + (wave << 10);
  const long rstep = (long)16 * K;

  const int fr = lane & 15, fc = (lane >> 4) << 3;

  for (int k0 = 0; k0 < K; k0 += 32) {
    __syncthreads();
    gld16(ga + k0,         la);
    gld16(ga + k0 + rstep, la + 512);
    gld16(gb + k0,         lb);
    gld16(gb + k0 + rstep, lb + 512);
    __syncthreads();
    bf16x8 af[4], bf[4];
#pragma unroll
    for (int i = 0; i < 4; ++i)
      af[i] = as_bf(*(const u16x8*)&As[(wm + (i << 4) + fr) * 32 + fc]);
#pragma unroll
    for (int i = 0; i < 4; ++i)
      bf[i] = as_bf(*(const u16x8*)&Bs[(wn + (i << 4) + fr) * 32 + fc]);
#pragma unroll
    for (int mi = 0; mi < 4; ++mi)
#pragma unroll
      for (int ni = 0; ni < 4; ++ni)
        acc[mi][ni] = __builtin_amdgcn_mfma_f32_16x16x32_bf16(af[mi], bf[ni], acc[mi][ni], 0, 0, 0);
  }

  const int er = (lane >> 4) << 2, ec = lane & 15;
#pragma unroll
  for (int mi = 0; mi < 4; ++mi)
#pragma unroll
    for (int ni = 0; ni < 4; ++ni) {
      float* cp = C + (m0 + wm + (mi << 4) + er) * N + (n0 + wn + (ni << 4) + ec);
#pragma unroll
      for (int r = 0; r < 4; ++r)
        cp[(long)r * N] = acc[mi][ni][r];
    }
}

// ---------------------------------------------------------------------------
// RMSNorm + RoPE (unchanged — verified)
// ---------------------------------------------------------------------------
__global__ __launch_bounds__(256) void norm_rope(
    u16* __restrict__ buf, const float* __restrict__ w,
    const float* __restrict__ cosb, const float* __restrict__ sinb,
    int sshift, float scale)
{
  const int row  = blockIdx.x * 4 + (threadIdx.x >> 6);
  const int lane = threadIdx.x & 63;
  const int s = (row >> sshift) & (S_LEN - 1);
  u16* p = buf + (long)row * HD;
  float t1 = bf2f(p[lane]), t2 = bf2f(p[lane + 64]);
  float ss = t1 * t1 + t2 * t2;
#pragma unroll
  for (int off = 32; off; off >>= 1) ss += __shfl_xor(ss, off);
  const float r = rsqrtf(ss * (1.0f / 128.0f) + 1e-5f);
  t1 *= r * w[lane];
  t2 *= r * w[lane + 64];
  const float* cp = cosb + s * HD;
  const float* sp = sinb + s * HD;
  const float o1 = (t1 * cp[lane]      - t2 * sp[lane])      * scale;
  const float o2 = (t2 * cp[lane + 64] + t1 * sp[lane + 64]) * scale;
  p[lane]      = f2bf(o1);
  p[lane + 64] = f2bf(o2);
}

// ---------------------------------------------------------------------------
// V (B*S, KV*HD) -> Vt (B*KV, HD, S). 8x8 register transpose per thread:
// scattered 16B reads (L2-absorbed), fully coalesced 16B writes.
// ---------------------------------------------------------------------------
__global__ __launch_bounds__(256) void transpose_v(const u16* __restrict__ v,
                                                   u16* __restrict__ vt)
{
  const int idx = blockIdx.x * 256 + threadIdx.x;   // 32768 threads
  const int t0  = (idx & 255) << 3;
  const int hd0 = ((idx >> 8) & 15) << 3;
  const int bkv = idx >> 12;                        // 0..7 = b*4+kv
  const u16* vp = v + ((long)(bkv >> 2) * S_LEN + t0) * 512 + ((bkv & 3) << 7) + hd0;
  u16x8 rw[8];
#pragma unroll
  for (int c = 0; c < 8; ++c) rw[c] = *(const u16x8*)(vp + (long)c * 512);
  u16* op = vt + ((long)bkv * HD + hd0) * S_LEN + t0;
#pragma unroll
  for (int j = 0; j < 8; ++j) {
    u16x8 o;
#pragma unroll
    for (int c = 0; c < 8; ++c) o[c] = rw[c][j];
    *(u16x8*)(op + (long)j * S_LEN) = o;
  }
}

// ---------------------------------------------------------------------------
// Flash attention, S^T/O^T, BT=64 tiles, t-split over 2 blocks (flash-decoding).
// Block = (bh, qt, par): handles jt in {par, par+2, ...} <= 2*qt+1 (exactly
// qt+1 tiles per par). Writes UN-normalized O~ (bf16) + (m, l) per q row;
// merge kernel combines the two partials. 32KB LDS -> 3+ blocks/CU resident.
// ---------------------------------------------------------------------------
__global__ __launch_bounds__(256, 3) void flash(
    const u16* __restrict__ q, const u16* __restrict__ k,
    const u16* __restrict__ vt, u16* __restrict__ ctx0,
    u16* __restrict__ ctx1, float* __restrict__ ml)
{
  __shared__ u16 Ks[64 * 128];    // K tile [t 64][d 128]; P overlay [q 128][t 64]
  __shared__ u16 Vs[128 * 64];    // Vt tile [hd 128][t 64]
  const int tid = threadIdx.x, wave = tid >> 6, lane = tid & 63;
  const int bx  = blockIdx.x;                       // 1024 blocks
  const int par = bx & 1;
  const int qtr = (bx >> 1) & 15;
  const int bh  = bx >> 5;                          // 0..31 = b*16+h
  const int qt  = (bh < 16) ? (15 - qtr) : qtr;     // balance causal wedge
  const int b   = bh >> 4, h = bh & 15;
  const int kv  = h >> 2;
  const int q0  = qt << 7;
  u16* ctx = par ? ctx1 : ctx0;

  const int fr = lane & 15, fhi = lane >> 4;

  // Q fragments, B-operand layout (n=fr, k=fhi*8+j): qf[nq][kb]
  bf16x8 qf[2][4];
#pragma unroll
  for (int nq = 0; nq < 2; ++nq) {
    const long s = q0 + (wave << 5) + (nq << 4) + fr;
    const u16* qp = q + ((long)b * S_LEN + s) * DMODEL + h * HD;
#pragma unroll
    for (int kb = 0; kb < 4; ++kb)
      qf[nq][kb] = as_bf(*(const u16x8*)(qp + (kb << 5) + (fhi << 3)));
  }

  f32x4 O[8][2] = {};            // O^T: [hd-tile][q-tile], col q = fr
  float mS[2] = {-1e30f, -1e30f}, lS[2] = {0.f, 0.f};

  const u16* kbase = k + ((long)b * S_LEN) * 512 + kv * HD;
  const u16* vbase = vt + ((long)(b * NKV + kv)) * HD * S_LEN;

  for (int jt = par; jt <= 2 * qt + 1; jt += 2) {
    const int t0 = jt << 6;
    __syncthreads();             // prev iter done with Ks(P) and Vs
    // stage K[t 64][d 128]: wave stages 16 rows (4 gld16, 4 rows each)
#pragma unroll
    for (int i = 0; i < 4; ++i) {
      const int row = (wave << 4) + (i << 2) + fhi;
      const int gc  = fr ^ (row & 15);
      gld16(kbase + (long)(t0 + row) * 512 + (gc << 3),
            Ks + (((wave << 4) + (i << 2)) << 7));
    }
    // stage Vt[hd 128][t 64]: wave stages 32 rows (4 gld16, 8 rows each)
#pragma unroll
    for (int i = 0; i < 4; ++i) {
      const int row = (wave << 5) + (i << 3) + (lane >> 3);
      const int gc8 = (lane & 7) ^ (row & 7);
      gld16(vbase + (long)row * S_LEN + t0 + (gc8 << 3),
            Vs + (((wave << 5) + (i << 3)) << 6));
    }
    __syncthreads();

    // S^T = K Q^T : Sac[mt 0..3][nq], rows t = mt*16 + fhi*4 + r, cols q = fr
    f32x4 Sac[4][2] = {};
#pragma unroll
    for (int mt = 0; mt < 4; ++mt) {
      const int t = (mt << 4) + fr;
      bf16x8 kf[4];
#pragma unroll
      for (int kb = 0; kb < 4; ++kb) {
        const int cc = ((kb << 2) + fhi) ^ (t & 15);
        kf[kb] = as_bf(*(const u16x8*)&Ks[t * 128 + (cc << 3)]);
      }
#pragma unroll
      for (int nq = 0; nq < 2; ++nq)
#pragma unroll
        for (int kb = 0; kb < 4; ++kb)
          Sac[mt][nq] = __builtin_amdgcn_mfma_f32_16x16x32_bf16(kf[kb], qf[nq][kb], Sac[mt][nq], 0, 0, 0);
    }

    // causal mask on the two diagonal tiles (jt>>1 == qt)
    if ((jt >> 1) == qt) {
      const int tbase = ((jt & 1) << 6) + (fhi << 2);
#pragma unroll
      for (int mt = 0; mt < 4; ++mt)
#pragma unroll
        for (int nq = 0; nq < 2; ++nq) {
          const int qin = (wave << 5) + (nq << 4) + fr;
#pragma unroll
          for (int r = 0; r < 4; ++r)
            if ((mt << 4) + tbase + r > qin) Sac[mt][nq][r] = -1e30f;
        }
    }

    // online softmax per q (= per lane, per nq)
#pragma unroll
    for (int nq = 0; nq < 2; ++nq) {
      float rmax = -1e30f;
#pragma unroll
      for (int mt = 0; mt < 4; ++mt)
#pragma unroll
        for (int r = 0; r < 4; ++r) rmax = fmaxf(rmax, Sac[mt][nq][r]);
      rmax = fmaxf(rmax, __shfl_xor(rmax, 16));
      rmax = fmaxf(rmax, __shfl_xor(rmax, 32));
      const float mn = fmaxf(mS[nq], rmax);
      const float al = __expf(mS[nq] - mn);
      mS[nq] = mn;
      float rsum = 0.f;
#pragma unroll
      for (int mt = 0; mt < 4; ++mt)
#pragma unroll
        for (int r = 0; r < 4; ++r) {
          const float e = __expf(Sac[mt][nq][r] - mn);
          Sac[mt][nq][r] = e;
          rsum += e;
        }
      rsum += __shfl_xor(rsum, 16);
      rsum += __shfl_xor(rsum, 32);
      lS[nq] = lS[nq] * al + rsum;
#pragma unroll
      for (int mh = 0; mh < 8; ++mh)
#pragma unroll
        for (int r = 0; r < 4; ++r) O[mh][nq][r] *= al;
    }

    __syncthreads();             // all waves done reading K from Ks

    // P[q 128][t 64] into Ks overlay: b64 writes, chunk8' = chunk8 ^ (q&7)
#pragma unroll
    for (int nq = 0; nq < 2; ++nq) {
      const int qrow = (wave << 5) + (nq << 4) + fr;
#pragma unroll
      for (int mt = 0; mt < 4; ++mt) {
        u16x4 pk;
#pragma unroll
        for (int r = 0; r < 4; ++r) pk[r] = f2bf(Sac[mt][nq][r]);
        const int cs = ((mt << 1) + (fhi >> 1)) ^ (fr & 7);
        *(u16x4*)&Ks[qrow * 64 + (cs << 3) + ((fhi & 1) << 2)] = pk;
      }
    }
    asm volatile("" ::: "memory");

    // O^T += V^T P^T (P rows wave-private -> no extra barrier)
    bf16x8 pf[2][2];
#pragma unroll
    for (int nq = 0; nq < 2; ++nq) {
      const int qrow = (wave << 5) + (nq << 4) + fr;
#pragma unroll
      for (int kt = 0; kt < 2; ++kt) {
        const int cs = ((kt << 2) + fhi) ^ (fr & 7);
        pf[nq][kt] = as_bf(*(const u16x8*)&Ks[qrow * 64 + (cs << 3)]);
      }
    }
#pragma unroll
    for (int mh = 0; mh < 8; ++mh) {
      const int hd = (mh << 4) + fr;
      bf16x8 vf[2];
#pragma unroll
      for (int kt = 0; kt < 2; ++kt) {
        const int cc = ((kt << 2) + fhi) ^ (hd & 7);
        vf[kt] = as_bf(*(const u16x8*)&Vs[hd * 64 + (cc << 3)]);
      }
#pragma unroll
      for (int nq = 0; nq < 2; ++nq)
#pragma unroll
        for (int kt = 0; kt < 2; ++kt)
          O[mh][nq] = __builtin_amdgcn_mfma_f32_16x16x32_bf16(vf[kt], pf[nq][kt], O[mh][nq], 0, 0, 0);
    }
  }

  // epilogue: write UN-normalized O~ + (m, l) per q row
#pragma unroll
  for (int nq = 0; nq < 2; ++nq) {
    const int qabs = q0 + (wave << 5) + (nq << 4) + fr;
    u16* cp = ctx + ((long)b * S_LEN + qabs) * DMODEL + h * HD;
#pragma unroll
    for (int mh = 0; mh < 8; ++mh) {
      u16x4 pk;
#pragma unroll
      for (int r = 0; r < 4; ++r) pk[r] = f2bf(O[mh][nq][r]);
      *(u16x4*)(cp + (mh << 4) + (fhi << 2)) = pk;
    }
    if (fhi == 0) {
      float* mlp = ml + ((((long)bh << 11) + qabs) << 2) + (par << 1);
      mlp[0] = mS[nq];
      mlp[1] = lS[nq];
    }
  }
}

// ---------------------------------------------------------------------------
// Merge the two t-split partials: out = (O0*a0 + O1*a1) / (l0*a0 + l1*a1),
// a_i = exp(m_i - max(m0,m1)). In-place over ctx0.
// ---------------------------------------------------------------------------
__global__ __launch_bounds__(256) void merge(
    const u16* __restrict__ c0, const u16* __restrict__ c1,
    const float* __restrict__ ml, u16* __restrict__ out)
{
  const int idx = blockIdx.x * 256 + threadIdx.x;   // 1048576 threads
  const long e8 = (long)idx << 3;
  const int bq = (int)(e8 >> 11);                   // b*2048 + s
  const int h  = ((int)e8 & 2047) >> 7;
  const int b  = bq >> 11, s = bq & 2047;
  const float* mlp = ml + ((((long)(b * 16 + h) << 11) + s) << 2);
  const float m0 = mlp[0], l0 = mlp[1], m1 = mlp[2], l1 = mlp[3];
  const float m  = fmaxf(m0, m1);
  const float a0 = __expf(m0 - m), a1 = __expf(m1 - m);
  const float inv = 1.0f / (l0 * a0 + l1 * a1);
  u16x8 x0 = *(const u16x8*)(c0 + e8);
  u16x8 x1 = *(const u16x8*)(c1 + e8);
  u16x8 o;
#pragma unroll
  for (int j = 0; j < 8; ++j)
    o[j] = f2bf((bf2f(x0[j]) * a0 + bf2f(x1[j]) * a1) * inv);
  *(u16x8*)(out + e8) = o;
}

// ---------------------------------------------------------------------------
extern "C" void kernel_launch(void* const* d_in, const int* in_sizes, int n_in,
                              void* d_out, int out_size, void* d_ws, size_t ws_size,
                              hipStream_t stream) {
  const float* x    = (const float*)d_in[0];
  // d_in[1] = mask (causal, analytic — unused)
  const float* cosb = (const float*)d_in[2];
  const float* sinb = (const float*)d_in[3];
  const float* Wq   = (const float*)d_in[4];
  const float* Wk   = (const float*)d_in[5];
  const float* Wv   = (const float*)d_in[6];
  const float* Wo   = (const float*)d_in[7];
  const float* qw   = (const float*)d_in[8];
  const float* kw   = (const float*)d_in[9];

  // d_out (33.55 MB): [qb 16.78 MB bf16 | xb->ctx1 16.78 MB bf16]
  u16* qb   = (u16*)d_out;
  u16* xb   = qb + 8388608;          // dead after gemm_qkv; reborn as ctx1
  u16* ctx1 = xb;
  // ws (~30.4 MB): kb | vb | vtb | ctx0 (pre-flash: Wall overlay) | ml
  u16* kb   = (u16*)d_ws;            // 2097152 elems
  u16* vb   = kb  + 2097152;
  u16* vtb  = vb  + 2097152;
  u16* ctx0 = vtb + 2097152;         // 8388608 elems
  u16* wall = ctx0;                  // (3072,2048) bf16, dies before flash
  u16* wob  = kb;                    // (2048,2048) bf16 over kb+vb, post-flash
  float* ml = (float*)(ctx0 + 8388608);  // 32*2048*4 floats = 1 MB
  float* out = (float*)d_out;

  cvt1<<<dim3(4096), dim3(256), 0, stream>>>(x, xb, 1048576);
  cvt3<<<dim3(3072), dim3(256), 0, stream>>>(Wq, Wk, Wv, wall);
  gemm_qkv<<<dim3(768), dim3(256), 0, stream>>>(xb, wall, qb, kb, vb);
  norm_rope<<<dim3(16384), dim3(256), 0, stream>>>(qb, qw, cosb, sinb, 4, 0.08838834764831845f);
  norm_rope<<<dim3(4096),  dim3(256), 0, stream>>>(kb, kw, cosb, sinb, 2, 1.0f);
  transpose_v<<<dim3(128), dim3(256), 0, stream>>>(vb, vtb);
  flash<<<dim3(1024), dim3(256), 0, stream>>>(qb, kb, vtb, ctx0, ctx1, ml);
  merge<<<dim3(4096), dim3(256), 0, stream>>>(ctx0, ctx1, ml, ctx0);
  cvt1<<<dim3(2048), dim3(256), 0, stream>>>(Wo, wob, 524288);
  gemm_o<<<dim3(512), dim3(256), 0, stream>>>(ctx0, wob, out);
}

// Round 7
// 338.916 us; speedup vs baseline: 1.2109x; 1.2109x over previous
//
#include <hip/hip_runtime.h>

typedef unsigned short u16;
typedef __bf16 bf16x8 __attribute__((ext_vector_type(8)));
typedef float f32x4 __attribute__((ext_vector_type(4)));
typedef u16 u16x8 __attribute__((ext_vector_type(8)));
typedef u16 u16x4 __attribute__((ext_vector_type(4)));

static constexpr int S_LEN  = 2048;
static constexpr int DMODEL = 2048;
static constexpr int NKV    = 4;
static constexpr int HD     = 128;

__device__ __forceinline__ u16 f2bf(float f) {
  unsigned u = __builtin_bit_cast(unsigned, f);
  u += 0x7fffu + ((u >> 16) & 1u);
  return (u16)(u >> 16);
}
__device__ __forceinline__ float bf2f(u16 h) {
  unsigned u = ((unsigned)h) << 16;
  return __builtin_bit_cast(float, u);
}
__device__ __forceinline__ bf16x8 as_bf(u16x8 v) { return __builtin_bit_cast(bf16x8, v); }

__device__ __forceinline__ u16x8 cvt8(const float* p) {
  f32x4 lo = *(const f32x4*)p;
  f32x4 hi = *(const f32x4*)(p + 4);
  u16x8 r;
#pragma unroll
  for (int j = 0; j < 4; ++j) { r[j] = f2bf(lo[j]); r[j + 4] = f2bf(hi[j]); }
  return r;
}

// async global->LDS DMA, 16B/lane; LDS dest = wave-uniform base + lane*16.
__device__ __forceinline__ void gld16(const u16* g, u16* l) {
  auto gp = (const __attribute__((address_space(1))) unsigned*)(unsigned long long)g;
  auto lp = (__attribute__((address_space(3))) unsigned*)(unsigned)(unsigned long long)l;
  __builtin_amdgcn_global_load_lds(gp, lp, 16, 0, 0);
}

// ---------------------------------------------------------------------------
// All fp32 -> bf16 conversions in ONE launch:
//   x (1048576 groups) -> xb ; Wq|Wk|Wv (786432) -> wall ; Wo (524288) -> wob
// ---------------------------------------------------------------------------
__global__ __launch_bounds__(256) void cvt_all(
    const float* __restrict__ x,  const float* __restrict__ wq,
    const float* __restrict__ wk, const float* __restrict__ wv,
    const float* __restrict__ wo,
    u16* __restrict__ xb, u16* __restrict__ wall, u16* __restrict__ wob)
{
  const long i = (long)blockIdx.x * 256 + threadIdx.x;   // 2359296 total
  const float* src; u16* dst; long j, o;
  if (i < 1048576)      { src = x;  dst = xb;   j = i;           o = i; }
  else if (i < 1572864) { src = wq; dst = wall; j = i - 1048576; o = i - 1048576; }
  else if (i < 1703936) { src = wk; dst = wall; j = i - 1572864; o = i - 1048576; }
  else if (i < 1835008) { src = wv; dst = wall; j = i - 1703936; o = i - 1048576; }
  else                  { src = wo; dst = wob;  j = i - 1835008; o = i - 1835008; }
  *(u16x8*)(dst + o * 8) = cvt8(src + j * 8);
}

// ---------------------------------------------------------------------------
// Fused QKV projection (unchanged — verified round 5)
// ---------------------------------------------------------------------------
__global__ __launch_bounds__(256) void gemm_qkv(
    const u16* __restrict__ A, const u16* __restrict__ Bw,
    u16* __restrict__ Cq, u16* __restrict__ Ck, u16* __restrict__ Cv)
{
  constexpr int K = 2048;
  __shared__ u16 As[128 * 32];
  __shared__ u16 Bs[128 * 32];
  const int bx = blockIdx.x;
  const int bm = bx / 24, bn = bx % 24;
  const int tid = threadIdx.x, wave = tid >> 6, lane = tid & 63;
  const int wm = (wave & 1) << 6, wn = (wave >> 1) << 6;
  const long m0 = (long)bm << 7, n0 = (long)bn << 7;

  f32x4 acc[4][4] = {};

  const int srow = (wave << 5) + (lane >> 2);
  const int sch  = (lane & 3) << 3;
  const u16* ga = A  + (m0 + srow) * K + sch;
  const u16* gb = Bw + (n0 + srow) * K + sch;
  u16* la = As + (wave << 10);
  u16* lb = Bs + (wave << 10);
  const long rstep = (long)16 * K;

  const int fr = lane & 15, fc = (lane >> 4) << 3;

  for (int k0 = 0; k0 < K; k0 += 32) {
    __syncthreads();
    gld16(ga + k0,         la);
    gld16(ga + k0 + rstep, la + 512);
    gld16(gb + k0,         lb);
    gld16(gb + k0 + rstep, lb + 512);
    __syncthreads();
    bf16x8 af[4], bf[4];
#pragma unroll
    for (int i = 0; i < 4; ++i)
      af[i] = as_bf(*(const u16x8*)&As[(wm + (i << 4) + fr) * 32 + fc]);
#pragma unroll
    for (int i = 0; i < 4; ++i)
      bf[i] = as_bf(*(const u16x8*)&Bs[(wn + (i << 4) + fr) * 32 + fc]);
#pragma unroll
    for (int mi = 0; mi < 4; ++mi)
#pragma unroll
      for (int ni = 0; ni < 4; ++ni)
        acc[mi][ni] = __builtin_amdgcn_mfma_f32_16x16x32_bf16(af[mi], bf[ni], acc[mi][ni], 0, 0, 0);
  }

  u16* Cb; int N2; long c0;
  if (bn < 16)      { Cb = Cq; N2 = 2048; c0 = n0; }
  else if (bn < 20) { Cb = Ck; N2 = 512;  c0 = n0 - 2048; }
  else              { Cb = Cv; N2 = 512;  c0 = n0 - 2560; }

  const int er = (lane >> 4) << 2, ec = lane & 15;
#pragma unroll
  for (int mi = 0; mi < 4; ++mi)
#pragma unroll
    for (int ni = 0; ni < 4; ++ni) {
      u16* cp = Cb + (m0 + wm + (mi << 4) + er) * N2 + (c0 + wn + (ni << 4) + ec);
#pragma unroll
      for (int r = 0; r < 4; ++r)
        cp[(long)r * N2] = f2bf(acc[mi][ni][r]);
    }
}

// ---------------------------------------------------------------------------
// Output projection (unchanged — verified round 5)
// ---------------------------------------------------------------------------
__global__ __launch_bounds__(256) void gemm_o(
    const u16* __restrict__ A, const u16* __restrict__ Bw, float* __restrict__ C)
{
  constexpr int K = 2048, N = 2048;
  __shared__ u16 As[128 * 32];
  __shared__ u16 Bs[128 * 32];
  const int bx = blockIdx.x;
  const int bm = bx >> 4, bn = bx & 15;
  const int tid = threadIdx.x, wave = tid >> 6, lane = tid & 63;
  const int wm = (wave & 1) << 6, wn = (wave >> 1) << 6;
  const long m0 = (long)bm << 7, n0 = (long)bn << 7;

  f32x4 acc[4][4] = {};

  const int srow = (wave << 5) + (lane >> 2);
  const int sch  = (lane & 3) << 3;
  const u16* ga = A  + (m0 + srow) * K + sch;
  const u16* gb = Bw + (n0 + srow) * K + sch;
  u16* la = As + (wave << 10);
  u16* lb = Bs + (wave << 10);
  const long rstep = (long)16 * K;

  const int fr = lane & 15, fc = (lane >> 4) << 3;

  for (int k0 = 0; k0 < K; k0 += 32) {
    __syncthreads();
    gld16(ga + k0,         la);
    gld16(ga + k0 + rstep, la + 512);
    gld16(gb + k0,         lb);
    gld16(gb + k0 + rstep, lb + 512);
    __syncthreads();
    bf16x8 af[4], bf[4];
#pragma unroll
    for (int i = 0; i < 4; ++i)
      af[i] = as_bf(*(const u16x8*)&As[(wm + (i << 4) + fr) * 32 + fc]);
#pragma unroll
    for (int i = 0; i < 4; ++i)
      bf[i] = as_bf(*(const u16x8*)&Bs[(wn + (i << 4) + fr) * 32 + fc]);
#pragma unroll
    for (int mi = 0; mi < 4; ++mi)
#pragma unroll
      for (int ni = 0; ni < 4; ++ni)
        acc[mi][ni] = __builtin_amdgcn_mfma_f32_16x16x32_bf16(af[mi], bf[ni], acc[mi][ni], 0, 0, 0);
  }

  const int er = (lane >> 4) << 2, ec = lane & 15;
#pragma unroll
  for (int mi = 0; mi < 4; ++mi)
#pragma unroll
    for (int ni = 0; ni < 4; ++ni) {
      float* cp = C + (m0 + wm + (mi << 4) + er) * N + (n0 + wn + (ni << 4) + ec);
#pragma unroll
      for (int r = 0; r < 4; ++r)
        cp[(long)r * N] = acc[mi][ni][r];
    }
}

// ---------------------------------------------------------------------------
// RMSNorm + RoPE, q and k fused into one launch (blocks < 16384 -> q)
// ---------------------------------------------------------------------------
__global__ __launch_bounds__(256) void norm_rope2(
    u16* __restrict__ qb, u16* __restrict__ kb,
    const float* __restrict__ qw, const float* __restrict__ kw,
    const float* __restrict__ cosb, const float* __restrict__ sinb)
{
  const int bx = blockIdx.x;
  u16* buf; const float* w; int sshift; float scale; int row;
  if (bx < 16384) { buf = qb; w = qw; sshift = 4; scale = 0.08838834764831845f;
                    row = bx * 4 + (threadIdx.x >> 6); }
  else            { buf = kb; w = kw; sshift = 2; scale = 1.0f;
                    row = (bx - 16384) * 4 + (threadIdx.x >> 6); }
  const int lane = threadIdx.x & 63;
  const int s = (row >> sshift) & (S_LEN - 1);
  u16* p = buf + (long)row * HD;
  float t1 = bf2f(p[lane]), t2 = bf2f(p[lane + 64]);
  float ss = t1 * t1 + t2 * t2;
#pragma unroll
  for (int off = 32; off; off >>= 1) ss += __shfl_xor(ss, off);
  const float r = rsqrtf(ss * (1.0f / 128.0f) + 1e-5f);
  t1 *= r * w[lane];
  t2 *= r * w[lane + 64];
  const float* cp = cosb + s * HD;
  const float* sp = sinb + s * HD;
  const float o1 = (t1 * cp[lane]      - t2 * sp[lane])      * scale;
  const float o2 = (t2 * cp[lane + 64] + t1 * sp[lane + 64]) * scale;
  p[lane]      = f2bf(o1);
  p[lane + 64] = f2bf(o2);
}

// ---------------------------------------------------------------------------
// V (B*S, KV*HD) -> Vt (B*KV, HD, S). 8x8 register transpose per thread.
// ---------------------------------------------------------------------------
__global__ __launch_bounds__(256) void transpose_v(const u16* __restrict__ v,
                                                   u16* __restrict__ vt)
{
  const int idx = blockIdx.x * 256 + threadIdx.x;   // 32768 threads
  const int t0  = (idx & 255) << 3;
  const int hd0 = ((idx >> 8) & 15) << 3;
  const int bkv = idx >> 12;                        // 0..7 = b*4+kv
  const u16* vp = v + ((long)(bkv >> 2) * S_LEN + t0) * 512 + ((bkv & 3) << 7) + hd0;
  u16x8 rw[8];
#pragma unroll
  for (int c = 0; c < 8; ++c) rw[c] = *(const u16x8*)(vp + (long)c * 512);
  u16* op = vt + ((long)bkv * HD + hd0) * S_LEN + t0;
#pragma unroll
  for (int j = 0; j < 8; ++j) {
    u16x8 o;
#pragma unroll
    for (int c = 0; c < 8; ++c) o[c] = rw[c][j];
    *(u16x8*)(op + (long)j * S_LEN) = o;
  }
}

// ---------------------------------------------------------------------------
// Flash attention, S^T/O^T, BT=128 (round-5 structure) with NO-RESCALE
// softmax: RMS-normed q,k (scale folded) bound |s| <= sqrt(128) ~ 11.4, so
// exp(s) can't overflow fp32 -> skip online max entirely (no rmax shuffles,
// no alpha, no O-rescale). l = running sum of exp(s); normalize at the end.
// ---------------------------------------------------------------------------
__global__ __launch_bounds__(256, 2) void flash(
    const u16* __restrict__ q, const u16* __restrict__ k,
    const u16* __restrict__ vt, u16* __restrict__ ctx)
{
  __shared__ u16 Ks[128 * 128];   // K tile [t][d]; reused for P [q][t]
  __shared__ u16 Vs[128 * 128];   // Vt tile [hd][t]
  const int tid = threadIdx.x, wave = tid >> 6, lane = tid & 63;
  const int bx  = blockIdx.x;
  const int qtr = bx & 15;
  const int bh  = bx >> 4;                          // b*16+h
  const int qt  = (bx < 256) ? (15 - qtr) : qtr;    // balance causal wedge
  const int b   = bh >> 4, h = bh & 15;
  const int kv  = h >> 2;
  const int q0  = qt << 7;

  const int fr = lane & 15, fhi = lane >> 4;

  // Q fragments, B-operand layout (n=fr, k=fhi*8+j): qf[nq][kb]
  bf16x8 qf[2][4];
#pragma unroll
  for (int nq = 0; nq < 2; ++nq) {
    const long s = q0 + (wave << 5) + (nq << 4) + fr;
    const u16* qp = q + ((long)b * S_LEN + s) * DMODEL + h * HD;
#pragma unroll
    for (int kb = 0; kb < 4; ++kb)
      qf[nq][kb] = as_bf(*(const u16x8*)(qp + (kb << 5) + (fhi << 3)));
  }

  f32x4 O[8][2] = {};            // O^T: [hd-tile][q-tile], col q = fr
  float lS[2] = {0.f, 0.f};

  const u16* kbase = k + ((long)b * S_LEN) * 512 + kv * HD;
  const u16* vbase = vt + ((long)(b * NKV + kv)) * HD * S_LEN;

  for (int jt = 0; jt <= qt; ++jt) {
    const int t0 = jt << 7;
    __syncthreads();             // prev iter done with Ks(P) and Vs
    // stage K[t][d] and Vt[hd][t], chunk8 XOR swizzle on global side
#pragma unroll
    for (int i = 0; i < 8; ++i) {
      const int row = (wave << 5) + (i << 2) + fhi;
      const int gc  = fr ^ (row & 15);
      gld16(kbase + (long)(t0 + row) * 512 + (gc << 3),
            Ks + (((wave << 5) + (i << 2)) << 7));
      gld16(vbase + (long)row * S_LEN + t0 + (gc << 3),
            Vs + (((wave << 5) + (i << 2)) << 7));
    }
    __syncthreads();

    // S^T = K Q^T : Sac[mt][nq], rows t = mt*16 + fhi*4 + r, cols q = fr
    f32x4 Sac[8][2] = {};
#pragma unroll
    for (int mt = 0; mt < 8; ++mt) {
      const int t = (mt << 4) + fr;
      bf16x8 kf[4];
#pragma unroll
      for (int kb = 0; kb < 4; ++kb) {
        const int cc = ((kb << 2) + fhi) ^ (t & 15);
        kf[kb] = as_bf(*(const u16x8*)&Ks[t * 128 + (cc << 3)]);
      }
#pragma unroll
      for (int nq = 0; nq < 2; ++nq)
#pragma unroll
        for (int kb = 0; kb < 4; ++kb)
          Sac[mt][nq] = __builtin_amdgcn_mfma_f32_16x16x32_bf16(kf[kb], qf[nq][kb], Sac[mt][nq], 0, 0, 0);
    }

    // causal mask on diagonal tile: t_in > q_in -> -inf (exp -> 0)
    if (jt == qt) {
#pragma unroll
      for (int mt = 0; mt < 8; ++mt)
#pragma unroll
        for (int nq = 0; nq < 2; ++nq) {
          const int qin = (wave << 5) + (nq << 4) + fr;
#pragma unroll
          for (int r = 0; r < 4; ++r)
            if ((mt << 4) + (fhi << 2) + r > qin) Sac[mt][nq][r] = -1e30f;
        }
    }

    // no-rescale softmax: P = exp(S), l += sum (|S| <= 11.4 -> safe in fp32)
#pragma unroll
    for (int nq = 0; nq < 2; ++nq) {
      float rsum = 0.f;
#pragma unroll
      for (int mt = 0; mt < 8; ++mt)
#pragma unroll
        for (int r = 0; r < 4; ++r) {
          const float e = __expf(Sac[mt][nq][r]);
          Sac[mt][nq][r] = e;
          rsum += e;
        }
      rsum += __shfl_xor(rsum, 16);
      rsum += __shfl_xor(rsum, 32);
      lS[nq] += rsum;
    }

    __syncthreads();             // all waves done reading K from Ks

    // P[q][t] into Ks overlay: b64 writes, chunk8' = chunk8 ^ (q&7)
#pragma unroll
    for (int nq = 0; nq < 2; ++nq) {
      const int qrow = (wave << 5) + (nq << 4) + fr;
#pragma unroll
      for (int mt = 0; mt < 8; ++mt) {
        u16x4 pk;
#pragma unroll
        for (int r = 0; r < 4; ++r) pk[r] = f2bf(Sac[mt][nq][r]);
        const int cs = ((mt << 1) + (fhi >> 1)) ^ (fr & 7);
        *(u16x4*)&Ks[qrow * 128 + (cs << 3) + ((fhi & 1) << 2)] = pk;
      }
    }
    asm volatile("" ::: "memory");

    // O^T += V^T P^T (P rows wave-private -> no extra barrier)
    bf16x8 pf[2][4];
#pragma unroll
    for (int nq = 0; nq < 2; ++nq) {
      const int qrow = (wave << 5) + (nq << 4) + fr;
#pragma unroll
      for (int kt = 0; kt < 4; ++kt) {
        const int cs = ((kt << 2) + fhi) ^ (fr & 7);
        pf[nq][kt] = as_bf(*(const u16x8*)&Ks[qrow * 128 + (cs << 3)]);
      }
    }
#pragma unroll
    for (int mh = 0; mh < 8; ++mh) {
      const int hd = (mh << 4) + fr;
      bf16x8 vf[4];
#pragma unroll
      for (int kt = 0; kt < 4; ++kt) {
        const int cc = ((kt << 2) + fhi) ^ (hd & 15);
        vf[kt] = as_bf(*(const u16x8*)&Vs[hd * 128 + (cc << 3)]);
      }
#pragma unroll
      for (int nq = 0; nq < 2; ++nq)
#pragma unroll
        for (int kt = 0; kt < 4; ++kt)
          O[mh][nq] = __builtin_amdgcn_mfma_f32_16x16x32_bf16(vf[kt], pf[nq][kt], O[mh][nq], 0, 0, 0);
    }
  }

  // epilogue: normalize by 1/l, write ctx rows (b, s, h*HD + hd), 8B stores
#pragma unroll
  for (int nq = 0; nq < 2; ++nq) {
    const float inv = 1.0f / lS[nq];
    const long s = q0 + (wave << 5) + (nq << 4) + fr;
    u16* cp = ctx + ((long)b * S_LEN + s) * DMODEL + h * HD;
#pragma unroll
    for (int mh = 0; mh < 8; ++mh) {
      u16x4 pk;
#pragma unroll
      for (int r = 0; r < 4; ++r) pk[r] = f2bf(O[mh][nq][r] * inv);
      *(u16x4*)(cp + (mh << 4) + (fhi << 2)) = pk;
    }
  }
}

// ---------------------------------------------------------------------------
extern "C" void kernel_launch(void* const* d_in, const int* in_sizes, int n_in,
                              void* d_out, int out_size, void* d_ws, size_t ws_size,
                              hipStream_t stream) {
  const float* x    = (const float*)d_in[0];
  // d_in[1] = mask (causal, analytic — unused)
  const float* cosb = (const float*)d_in[2];
  const float* sinb = (const float*)d_in[3];
  const float* Wq   = (const float*)d_in[4];
  const float* Wk   = (const float*)d_in[5];
  const float* Wv   = (const float*)d_in[6];
  const float* Wo   = (const float*)d_in[7];
  const float* qw   = (const float*)d_in[8];
  const float* kw   = (const float*)d_in[9];

  // d_out (33.55 MB): [qb 16.78 MB bf16 | xb 16.78 MB bf16] — both dead by gemm_o
  u16* qb  = (u16*)d_out;
  u16* xb  = qb + 8388608;
  // ws (~37.2 MB, round-4 proved >= 45.6 MB usable):
  //   kb | vb | vtb | ctx (wall overlays ctx pre-flash) | wob
  u16* kb   = (u16*)d_ws;            // 2097152 elems
  u16* vb   = kb  + 2097152;
  u16* vtb  = vb  + 2097152;
  u16* ctx  = vtb + 2097152;         // 8388608 elems
  u16* wall = ctx;                   // (3072,2048) bf16, dies before flash
  u16* wob  = ctx + 8388608;         // (2048,2048) bf16, lives到 gemm_o
  float* out = (float*)d_out;

  cvt_all<<<dim3(9216), dim3(256), 0, stream>>>(x, Wq, Wk, Wv, Wo, xb, wall, wob);
  gemm_qkv<<<dim3(768), dim3(256), 0, stream>>>(xb, wall, qb, kb, vb);
  norm_rope2<<<dim3(20480), dim3(256), 0, stream>>>(qb, kb, qw, kw, cosb, sinb);
  transpose_v<<<dim3(128), dim3(256), 0, stream>>>(vb, vtb);
  flash<<<dim3(512), dim3(256), 0, stream>>>(qb, kb, vtb, ctx);
  gemm_o<<<dim3(512), dim3(256), 0, stream>>>(ctx, wob, out);
}

// Round 8
// 327.080 us; speedup vs baseline: 1.2547x; 1.0362x over previous
//
#include <hip/hip_runtime.h>

typedef unsigned short u16;
typedef __bf16 bf16x8 __attribute__((ext_vector_type(8)));
typedef float f32x4 __attribute__((ext_vector_type(4)));
typedef u16 u16x8 __attribute__((ext_vector_type(8)));
typedef u16 u16x4 __attribute__((ext_vector_type(4)));

static constexpr int S_LEN  = 2048;
static constexpr int DMODEL = 2048;
static constexpr int NKV    = 4;
static constexpr int HD     = 128;

__device__ __forceinline__ u16 f2bf(float f) {
  unsigned u = __builtin_bit_cast(unsigned, f);
  u += 0x7fffu + ((u >> 16) & 1u);
  return (u16)(u >> 16);
}
__device__ __forceinline__ float bf2f(u16 h) {
  unsigned u = ((unsigned)h) << 16;
  return __builtin_bit_cast(float, u);
}
__device__ __forceinline__ bf16x8 as_bf(u16x8 v) { return __builtin_bit_cast(bf16x8, v); }

__device__ __forceinline__ u16x8 cvt8(const float* p) {
  f32x4 lo = *(const f32x4*)p;
  f32x4 hi = *(const f32x4*)(p + 4);
  u16x8 r;
#pragma unroll
  for (int j = 0; j < 4; ++j) { r[j] = f2bf(lo[j]); r[j + 4] = f2bf(hi[j]); }
  return r;
}

// async global->LDS DMA, 16B/lane; LDS dest = wave-uniform base + lane*16.
__device__ __forceinline__ void gld16(const u16* g, u16* l) {
  auto gp = (const __attribute__((address_space(1))) unsigned*)(unsigned long long)g;
  auto lp = (__attribute__((address_space(3))) unsigned*)(unsigned)(unsigned long long)l;
  __builtin_amdgcn_global_load_lds(gp, lp, 16, 0, 0);
}

// ---------------------------------------------------------------------------
// All fp32 -> bf16 conversions in ONE launch (unchanged — verified)
// ---------------------------------------------------------------------------
__global__ __launch_bounds__(256) void cvt_all(
    const float* __restrict__ x,  const float* __restrict__ wq,
    const float* __restrict__ wk, const float* __restrict__ wv,
    const float* __restrict__ wo,
    u16* __restrict__ xb, u16* __restrict__ wall, u16* __restrict__ wob)
{
  const long i = (long)blockIdx.x * 256 + threadIdx.x;   // 2359296 total
  const float* src; u16* dst; long j, o;
  if (i < 1048576)      { src = x;  dst = xb;   j = i;           o = i; }
  else if (i < 1572864) { src = wq; dst = wall; j = i - 1048576; o = i - 1048576; }
  else if (i < 1703936) { src = wk; dst = wall; j = i - 1572864; o = i - 1048576; }
  else if (i < 1835008) { src = wv; dst = wall; j = i - 1703936; o = i - 1048576; }
  else                  { src = wo; dst = wob;  j = i - 1835008; o = i - 1835008; }
  *(u16x8*)(dst + o * 8) = cvt8(src + j * 8);
}

// ---------------------------------------------------------------------------
// Fused QKV projection, BK=64: 128x128 tile, 32 MFMA per barrier-pair
// (half the barrier crossings of BK=32), XOR chunk swizzle (8 chunks/row).
// LDS 32KB -> occupancy still VGPR-capped at 4 blocks/CU.
// ---------------------------------------------------------------------------
__global__ __launch_bounds__(256) void gemm_qkv(
    const u16* __restrict__ A, const u16* __restrict__ Bw,
    u16* __restrict__ Cq, u16* __restrict__ Ck, u16* __restrict__ Cv)
{
  constexpr int K = 2048;
  __shared__ u16 As[128 * 64];
  __shared__ u16 Bs[128 * 64];
  const int bx = blockIdx.x;
  const int bm = bx / 24, bn = bx % 24;
  const int tid = threadIdx.x, wave = tid >> 6, lane = tid & 63;
  const int wm = (wave & 1) << 6, wn = (wave >> 1) << 6;
  const long m0 = (long)bm << 7, n0 = (long)bn << 7;

  f32x4 acc[4][4] = {};

  // staging: lane l covers row wave*32 + l/8, LDS chunk l&7 which holds
  // global chunk (l&7)^(row&7) -> fragment read of global chunk g at row r
  // is LDS chunk g^(r&7).
  const int srow = (wave << 5) + (lane >> 3);
  const int sch  = ((lane & 7) ^ ((lane >> 3) & 7)) << 3;
  const u16* ga = A  + (m0 + srow) * K + sch;
  const u16* gb = Bw + (n0 + srow) * K + sch;
  u16* la = As + (wave << 11);
  u16* lb = Bs + (wave << 11);
  const long rstep = (long)8 * K;

  const int fr = lane & 15, fhi = lane >> 4;

  for (int k0 = 0; k0 < K; k0 += 64) {
    __syncthreads();
#pragma unroll
    for (int i = 0; i < 4; ++i) {
      gld16(ga + k0 + i * rstep, la + i * 512);
      gld16(gb + k0 + i * rstep, lb + i * 512);
    }
    __syncthreads();
#pragma unroll
    for (int kb = 0; kb < 2; ++kb) {
      bf16x8 af[4], bf[4];
#pragma unroll
      for (int i = 0; i < 4; ++i) {
        const int row = wm + (i << 4) + fr;
        const int cc  = (((kb << 2) + fhi) ^ (fr & 7)) << 3;
        af[i] = as_bf(*(const u16x8*)&As[row * 64 + cc]);
      }
#pragma unroll
      for (int i = 0; i < 4; ++i) {
        const int row = wn + (i << 4) + fr;
        const int cc  = (((kb << 2) + fhi) ^ (fr & 7)) << 3;
        bf[i] = as_bf(*(const u16x8*)&Bs[row * 64 + cc]);
      }
#pragma unroll
      for (int mi = 0; mi < 4; ++mi)
#pragma unroll
        for (int ni = 0; ni < 4; ++ni)
          acc[mi][ni] = __builtin_amdgcn_mfma_f32_16x16x32_bf16(af[mi], bf[ni], acc[mi][ni], 0, 0, 0);
    }
  }

  u16* Cb; int N2; long c0;
  if (bn < 16)      { Cb = Cq; N2 = 2048; c0 = n0; }
  else if (bn < 20) { Cb = Ck; N2 = 512;  c0 = n0 - 2048; }
  else              { Cb = Cv; N2 = 512;  c0 = n0 - 2560; }

  const int er = (lane >> 4) << 2, ec = lane & 15;
#pragma unroll
  for (int mi = 0; mi < 4; ++mi)
#pragma unroll
    for (int ni = 0; ni < 4; ++ni) {
      u16* cp = Cb + (m0 + wm + (mi << 4) + er) * N2 + (c0 + wn + (ni << 4) + ec);
#pragma unroll
      for (int r = 0; r < 4; ++r)
        cp[(long)r * N2] = f2bf(acc[mi][ni][r]);
    }
}

// ---------------------------------------------------------------------------
// Output projection, BK=64 (same recipe), fp32 C out.
// ---------------------------------------------------------------------------
__global__ __launch_bounds__(256) void gemm_o(
    const u16* __restrict__ A, const u16* __restrict__ Bw, float* __restrict__ C)
{
  constexpr int K = 2048, N = 2048;
  __shared__ u16 As[128 * 64];
  __shared__ u16 Bs[128 * 64];
  const int bx = blockIdx.x;
  const int bm = bx >> 4, bn = bx & 15;
  const int tid = threadIdx.x, wave = tid >> 6, lane = tid & 63;
  const int wm = (wave & 1) << 6, wn = (wave >> 1) << 6;
  const long m0 = (long)bm << 7, n0 = (long)bn << 7;

  f32x4 acc[4][4] = {};

  const int srow = (wave << 5) + (lane >> 3);
  const int sch  = ((lane & 7) ^ ((lane >> 3) & 7)) << 3;
  const u16* ga = A  + (m0 + srow) * K + sch;
  const u16* gb = Bw + (n0 + srow) * K + sch;
  u16* la = As + (wave << 11);
  u16* lb = Bs + (wave << 11);
  const long rstep = (long)8 * K;

  const int fr = lane & 15, fhi = lane >> 4;

  for (int k0 = 0; k0 < K; k0 += 64) {
    __syncthreads();
#pragma unroll
    for (int i = 0; i < 4; ++i) {
      gld16(ga + k0 + i * rstep, la + i * 512);
      gld16(gb + k0 + i * rstep, lb + i * 512);
    }
    __syncthreads();
#pragma unroll
    for (int kb = 0; kb < 2; ++kb) {
      bf16x8 af[4], bf[4];
#pragma unroll
      for (int i = 0; i < 4; ++i) {
        const int cc = (((kb << 2) + fhi) ^ (fr & 7)) << 3;
        af[i] = as_bf(*(const u16x8*)&As[(wm + (i << 4) + fr) * 64 + cc]);
        bf[i] = as_bf(*(const u16x8*)&Bs[(wn + (i << 4) + fr) * 64 + cc]);
      }
#pragma unroll
      for (int mi = 0; mi < 4; ++mi)
#pragma unroll
        for (int ni = 0; ni < 4; ++ni)
          acc[mi][ni] = __builtin_amdgcn_mfma_f32_16x16x32_bf16(af[mi], bf[ni], acc[mi][ni], 0, 0, 0);
    }
  }

  const int er = (lane >> 4) << 2, ec = lane & 15;
#pragma unroll
  for (int mi = 0; mi < 4; ++mi)
#pragma unroll
    for (int ni = 0; ni < 4; ++ni) {
      float* cp = C + (m0 + wm + (mi << 4) + er) * N + (n0 + wn + (ni << 4) + ec);
#pragma unroll
      for (int r = 0; r < 4; ++r)
        cp[(long)r * N] = acc[mi][ni][r];
    }
}

// ---------------------------------------------------------------------------
// k RMSNorm+RoPE (blocks < 4096) + V transpose (blocks >= 4096), one launch.
// ---------------------------------------------------------------------------
__global__ __launch_bounds__(256) void k_prep(
    u16* __restrict__ kb, const float* __restrict__ kw,
    const float* __restrict__ cosb, const float* __restrict__ sinb,
    const u16* __restrict__ v, u16* __restrict__ vt)
{
  const int bx = blockIdx.x;
  if (bx < 4096) {
    const int row  = bx * 4 + (threadIdx.x >> 6);
    const int lane = threadIdx.x & 63;
    const int s = (row >> 2) & (S_LEN - 1);
    u16* p = kb + (long)row * HD;
    float t1 = bf2f(p[lane]), t2 = bf2f(p[lane + 64]);
    float ss = t1 * t1 + t2 * t2;
#pragma unroll
    for (int off = 32; off; off >>= 1) ss += __shfl_xor(ss, off);
    const float r = rsqrtf(ss * (1.0f / 128.0f) + 1e-5f);
    t1 *= r * kw[lane];
    t2 *= r * kw[lane + 64];
    const float* cp = cosb + s * HD;
    const float* sp = sinb + s * HD;
    p[lane]      = f2bf(t1 * cp[lane]      - t2 * sp[lane]);
    p[lane + 64] = f2bf(t2 * cp[lane + 64] + t1 * sp[lane + 64]);
  } else {
    const int idx = (bx - 4096) * 256 + threadIdx.x;   // 32768 threads
    const int t0  = (idx & 255) << 3;
    const int hd0 = ((idx >> 8) & 15) << 3;
    const int bkv = idx >> 12;                         // 0..7 = b*4+kv
    const u16* vp = v + ((long)(bkv >> 2) * S_LEN + t0) * 512 + ((bkv & 3) << 7) + hd0;
    u16x8 rw[8];
#pragma unroll
    for (int c = 0; c < 8; ++c) rw[c] = *(const u16x8*)(vp + (long)c * 512);
    u16* op = vt + ((long)bkv * HD + hd0) * S_LEN + t0;
#pragma unroll
    for (int j = 0; j < 8; ++j) {
      u16x8 o;
#pragma unroll
      for (int c = 0; c < 8; ++c) o[c] = rw[c][j];
      *(u16x8*)(op + (long)j * S_LEN) = o;
    }
  }
}

// ---------------------------------------------------------------------------
// Flash attention, S^T/O^T, BT=128, no-rescale softmax (round-7 loop,
// verified) + FUSED q RMSNorm/RoPE/scale in the Q-fragment preamble:
// each q row is read by exactly one block; its 128 elems live in lanes
// (fr, fhi 0..3) -> 2 shuffles reduce; RoPE partner k^64 = kb^2, lane-local.
// ---------------------------------------------------------------------------
__global__ __launch_bounds__(256, 2) void flash(
    const u16* __restrict__ q, const u16* __restrict__ k,
    const u16* __restrict__ vt, u16* __restrict__ ctx,
    const float* __restrict__ qw,
    const float* __restrict__ cosb, const float* __restrict__ sinb)
{
  __shared__ u16 Ks[128 * 128];   // K tile [t][d]; reused for P [q][t]
  __shared__ u16 Vs[128 * 128];   // Vt tile [hd][t]
  const int tid = threadIdx.x, wave = tid >> 6, lane = tid & 63;
  const int bx  = blockIdx.x;
  const int qtr = bx & 15;
  const int bh  = bx >> 4;                          // b*16+h
  const int qt  = (bx < 256) ? (15 - qtr) : qtr;    // balance causal wedge
  const int b   = bh >> 4, h = bh & 15;
  const int kv  = h >> 2;
  const int q0  = qt << 7;

  const int fr = lane & 15, fhi = lane >> 4;

  // Q fragments with fused RMSNorm + RoPE + 1/sqrt(HD) scale
  bf16x8 qf[2][4];
#pragma unroll
  for (int nq = 0; nq < 2; ++nq) {
    const int srow = q0 + (wave << 5) + (nq << 4) + fr;   // 0..2047
    const u16* qp = q + ((long)b * S_LEN + srow) * DMODEL + h * HD;
    float qv[4][8];
    float ss = 0.f;
#pragma unroll
    for (int kb = 0; kb < 4; ++kb) {
      u16x8 raw = *(const u16x8*)(qp + (kb << 5) + (fhi << 3));
#pragma unroll
      for (int j = 0; j < 8; ++j) {
        const float v = bf2f(raw[j]);
        qv[kb][j] = v;
        ss += v * v;
      }
    }
    ss += __shfl_xor(ss, 16);
    ss += __shfl_xor(ss, 32);
    const float rn = rsqrtf(ss * (1.0f / 128.0f) + 1e-5f);
    const float* cp = cosb + srow * HD;
    const float* sp = sinb + srow * HD;
#pragma unroll
    for (int kb = 0; kb < 4; ++kb) {
      u16x8 pk;
#pragma unroll
      for (int j = 0; j < 8; ++j) {
        const int kk = (kb << 5) + (fhi << 3) + j;
        const float tk = qv[kb][j]     * rn * qw[kk];
        const float tp = qv[kb ^ 2][j] * rn * qw[kk ^ 64];
        const float o = (tk * cp[kk] + ((kb < 2) ? -tp : tp) * sp[kk])
                        * 0.08838834764831845f;
        pk[j] = f2bf(o);
      }
      qf[nq][kb] = as_bf(pk);
    }
  }

  f32x4 O[8][2] = {};            // O^T: [hd-tile][q-tile], col q = fr
  float lS[2] = {0.f, 0.f};

  const u16* kbase = k + ((long)b * S_LEN) * 512 + kv * HD;
  const u16* vbase = vt + ((long)(b * NKV + kv)) * HD * S_LEN;

  for (int jt = 0; jt <= qt; ++jt) {
    const int t0 = jt << 7;
    __syncthreads();             // prev iter done with Ks(P) and Vs
#pragma unroll
    for (int i = 0; i < 8; ++i) {
      const int row = (wave << 5) + (i << 2) + fhi;
      const int gc  = fr ^ (row & 15);
      gld16(kbase + (long)(t0 + row) * 512 + (gc << 3),
            Ks + (((wave << 5) + (i << 2)) << 7));
      gld16(vbase + (long)row * S_LEN + t0 + (gc << 3),
            Vs + (((wave << 5) + (i << 2)) << 7));
    }
    __syncthreads();

    // S^T = K Q^T
    f32x4 Sac[8][2] = {};
#pragma unroll
    for (int mt = 0; mt < 8; ++mt) {
      const int t = (mt << 4) + fr;
      bf16x8 kf[4];
#pragma unroll
      for (int kb = 0; kb < 4; ++kb) {
        const int cc = ((kb << 2) + fhi) ^ (t & 15);
        kf[kb] = as_bf(*(const u16x8*)&Ks[t * 128 + (cc << 3)]);
      }
#pragma unroll
      for (int nq = 0; nq < 2; ++nq)
#pragma unroll
        for (int kb = 0; kb < 4; ++kb)
          Sac[mt][nq] = __builtin_amdgcn_mfma_f32_16x16x32_bf16(kf[kb], qf[nq][kb], Sac[mt][nq], 0, 0, 0);
    }

    // causal mask on diagonal tile
    if (jt == qt) {
#pragma unroll
      for (int mt = 0; mt < 8; ++mt)
#pragma unroll
        for (int nq = 0; nq < 2; ++nq) {
          const int qin = (wave << 5) + (nq << 4) + fr;
#pragma unroll
          for (int r = 0; r < 4; ++r)
            if ((mt << 4) + (fhi << 2) + r > qin) Sac[mt][nq][r] = -1e30f;
        }
    }

    // no-rescale softmax (|s| <= sqrt(128): exp can't overflow)
#pragma unroll
    for (int nq = 0; nq < 2; ++nq) {
      float rsum = 0.f;
#pragma unroll
      for (int mt = 0; mt < 8; ++mt)
#pragma unroll
        for (int r = 0; r < 4; ++r) {
          const float e = __expf(Sac[mt][nq][r]);
          Sac[mt][nq][r] = e;
          rsum += e;
        }
      rsum += __shfl_xor(rsum, 16);
      rsum += __shfl_xor(rsum, 32);
      lS[nq] += rsum;
    }

    __syncthreads();             // all waves done reading K from Ks

    // P[q][t] into Ks overlay: b64 writes, chunk8' = chunk8 ^ (q&7)
#pragma unroll
    for (int nq = 0; nq < 2; ++nq) {
      const int qrow = (wave << 5) + (nq << 4) + fr;
#pragma unroll
      for (int mt = 0; mt < 8; ++mt) {
        u16x4 pk;
#pragma unroll
        for (int r = 0; r < 4; ++r) pk[r] = f2bf(Sac[mt][nq][r]);
        const int cs = ((mt << 1) + (fhi >> 1)) ^ (fr & 7);
        *(u16x4*)&Ks[qrow * 128 + (cs << 3) + ((fhi & 1) << 2)] = pk;
      }
    }
    asm volatile("" ::: "memory");

    // O^T += V^T P^T
    bf16x8 pf[2][4];
#pragma unroll
    for (int nq = 0; nq < 2; ++nq) {
      const int qrow = (wave << 5) + (nq << 4) + fr;
#pragma unroll
      for (int kt = 0; kt < 4; ++kt) {
        const int cs = ((kt << 2) + fhi) ^ (fr & 7);
        pf[nq][kt] = as_bf(*(const u16x8*)&Ks[qrow * 128 + (cs << 3)]);
      }
    }
#pragma unroll
    for (int mh = 0; mh < 8; ++mh) {
      const int hd = (mh << 4) + fr;
      bf16x8 vf[4];
#pragma unroll
      for (int kt = 0; kt < 4; ++kt) {
        const int cc = ((kt << 2) + fhi) ^ (hd & 15);
        vf[kt] = as_bf(*(const u16x8*)&Vs[hd * 128 + (cc << 3)]);
      }
#pragma unroll
      for (int nq = 0; nq < 2; ++nq)
#pragma unroll
        for (int kt = 0; kt < 4; ++kt)
          O[mh][nq] = __builtin_amdgcn_mfma_f32_16x16x32_bf16(vf[kt], pf[nq][kt], O[mh][nq], 0, 0, 0);
    }
  }

  // epilogue
#pragma unroll
  for (int nq = 0; nq < 2; ++nq) {
    const float inv = 1.0f / lS[nq];
    const long s = q0 + (wave << 5) + (nq << 4) + fr;
    u16* cp = ctx + ((long)b * S_LEN + s) * DMODEL + h * HD;
#pragma unroll
    for (int mh = 0; mh < 8; ++mh) {
      u16x4 pk;
#pragma unroll
      for (int r = 0; r < 4; ++r) pk[r] = f2bf(O[mh][nq][r] * inv);
      *(u16x4*)(cp + (mh << 4) + (fhi << 2)) = pk;
    }
  }
}

// ---------------------------------------------------------------------------
extern "C" void kernel_launch(void* const* d_in, const int* in_sizes, int n_in,
                              void* d_out, int out_size, void* d_ws, size_t ws_size,
                              hipStream_t stream) {
  const float* x    = (const float*)d_in[0];
  // d_in[1] = mask (causal, analytic — unused)
  const float* cosb = (const float*)d_in[2];
  const float* sinb = (const float*)d_in[3];
  const float* Wq   = (const float*)d_in[4];
  const float* Wk   = (const float*)d_in[5];
  const float* Wv   = (const float*)d_in[6];
  const float* Wo   = (const float*)d_in[7];
  const float* qw   = (const float*)d_in[8];
  const float* kw   = (const float*)d_in[9];

  // d_out (33.55 MB): [qb 16.78 MB bf16 | xb 16.78 MB bf16] — both dead by gemm_o
  u16* qb  = (u16*)d_out;
  u16* xb  = qb + 8388608;
  // ws: kb | vb | vtb | ctx (wall overlays ctx pre-flash) | wob
  u16* kb   = (u16*)d_ws;            // 2097152 elems
  u16* vb   = kb  + 2097152;
  u16* vtb  = vb  + 2097152;
  u16* ctx  = vtb + 2097152;         // 8388608 elems
  u16* wall = ctx;                   // (3072,2048) bf16, dies before flash
  u16* wob  = ctx + 8388608;         // (2048,2048) bf16, lives until gemm_o
  float* out = (float*)d_out;

  cvt_all<<<dim3(9216), dim3(256), 0, stream>>>(x, Wq, Wk, Wv, Wo, xb, wall, wob);
  gemm_qkv<<<dim3(768), dim3(256), 0, stream>>>(xb, wall, qb, kb, vb);
  k_prep<<<dim3(4224), dim3(256), 0, stream>>>(kb, kw, cosb, sinb, vb, vtb);
  flash<<<dim3(512), dim3(256), 0, stream>>>(qb, kb, vtb, ctx, qw, cosb, sinb);
  gemm_o<<<dim3(512), dim3(256), 0, stream>>>(ctx, wob, out);
}